// Round 7
// baseline (336.389 us; speedup 1.0000x reference)
//
#include <hip/hip_runtime.h>
#include <hip/hip_bf16.h>

// ---------------------------------------------------------------------------
// NHRepNet fused forward, Round 7: wave-local network (zero LDS, zero barriers
// needed). Each wave carries 32 points through all 8 layers in registers.
//
// Trick: permute the weight prepack so the MFMA C-layout chains directly into
// the next layer's B-operand as a register relabel.
//   Logical channel of C-slot (M, q, r) := M*16 + q*4 + r  (q=lane>>4, r=reg)
//   B-frag assignment: b[nt][kk].elem[j] = act(acc[M=2kk+(j>>2)][nt][r=j&3])
//   => contraction slot (kk, q, j) carries channel
//      sigma = kk*32 + (j>>2)*16 + q*4 + (j&3)
//   Prepack A with in-index sigma (out-index unchanged: o = M*16 + (lane&15)).
// Consequences:
//   - x enters layer 0 at slots q==0, j=0..2 of kk=0 (sigma=j there).
//   - layer-3 skip splice (logical ch 253/254/255) = lanes q==3,
//     b[nt][7].elem[5..7] <- bf16(x), W4 rows absorb all scales (as R4).
//   - acc[16][2] f32x4 = 128 AGPR; b[2][8] bf16x8 = 64 VGPR; A-frags streamed
//     from L2 in 8-frag groups. 256-reg tier: __launch_bounds__(256,2).
//   - A-frag addresses are identical across all waves; per-layer
//     __syncthreads() convoys the block's 4 waves for L1 temporal reuse.
// R6 lesson honored: do NOT exceed the register tier (spill = 145MB HBM writes).
// ---------------------------------------------------------------------------

using bf16x8 = __attribute__((ext_vector_type(8))) __bf16;
using f32x4  = __attribute__((ext_vector_type(4))) float;

#define OFFW0 0
#define OFFW1 8192
#define OFFW2 73728
#define OFFW3 139264
#define OFFW4 204800
#define OFFW5 270336
#define OFFW6 335872
#define OFFW7 401408
#define WSB_BYTE_OFF 811008   // fp32 bias region
#define OFFB7 1792            // L0..L6 at l*256; L7 at 1792 (16 floats, padded)

#define SCALE_T2 144.26950408889634f      // 100*log2(e)
#define INV_SQRT2 0.70710678118654752f
#define LN2_100 0.0069314718055994531f    // ln2/100

__device__ __forceinline__ float fast_exp2(float x) {
#if __has_builtin(__builtin_amdgcn_exp2f)
    return __builtin_amdgcn_exp2f(x);
#else
    return exp2f(x);
#endif
}
__device__ __forceinline__ float fast_log2(float x) {
#if __has_builtin(__builtin_amdgcn_logf)
    return __builtin_amdgcn_logf(x);
#else
    return log2f(x);
#endif
}

// a2 = max(t2,0) + log2(1 + 2^-|t2|)   (t2-domain softplus, scales folded in W)
__device__ __forceinline__ float softplus_t2(float t2) {
    float e = fast_exp2(-fabsf(t2));
    float l = fast_log2(1.0f + e);
    return fmaxf(t2, 0.0f) + l;
}

__device__ __forceinline__ unsigned short bf16_rne(float f) {
    unsigned int u = __float_as_uint(f);
    unsigned int r = u + 0x7FFFu + ((u >> 16) & 1u);
    return (unsigned short)(r >> 16);
}

union frag_u {
    bf16x8 v;
    unsigned short s[8];
    uint4 u4;
};

__device__ __forceinline__ unsigned int bits2(__hip_bfloat162 h) {
    union { __hip_bfloat162 h; unsigned int u; } c;
    c.h = h;
    return c.u;
}

// b-frag from two activated accumulators (j=0..3 <- aM=2kk, j=4..7 <- aM=2kk+1)
__device__ __forceinline__ bf16x8 sp_pack(f32x4 a, f32x4 c) {
    frag_u u;
    u.u4.x = bits2(__float22bfloat162_rn(float2{softplus_t2(a[0]), softplus_t2(a[1])}));
    u.u4.y = bits2(__float22bfloat162_rn(float2{softplus_t2(a[2]), softplus_t2(a[3])}));
    u.u4.z = bits2(__float22bfloat162_rn(float2{softplus_t2(c[0]), softplus_t2(c[1])}));
    u.u4.w = bits2(__float22bfloat162_rn(float2{softplus_t2(c[2]), softplus_t2(c[3])}));
    return u.v;
}

// Full 256->256 layer, K=256 (8 kk-blocks). wl = layer frag base + lane*8.
__device__ __forceinline__ void layer_K256(
    const unsigned short* __restrict__ wl, const float* __restrict__ bias,
    f32x4 (&acc)[16][2], bf16x8 (&b)[2][8], int q)
{
#pragma unroll
    for (int M = 0; M < 16; ++M) {
        float4 b4 = *(const float4*)(bias + M * 16 + q * 4);
        f32x4 bv = {b4.x, b4.y, b4.z, b4.w};
        acc[M][0] = bv;
        acc[M][1] = bv;
    }
#pragma unroll
    for (int kk = 0; kk < 8; ++kk) {
#pragma unroll
        for (int Mh = 0; Mh < 2; ++Mh) {
            bf16x8 af[8];
#pragma unroll
            for (int mi = 0; mi < 8; ++mi)
                af[mi] = *(const bf16x8*)(wl + (((Mh * 8 + mi) * 8 + kk) * 512));
#pragma unroll
            for (int mi = 0; mi < 8; ++mi) {
                const int M = Mh * 8 + mi;
                acc[M][0] = __builtin_amdgcn_mfma_f32_16x16x32_bf16(af[mi], b[0][kk], acc[M][0], 0, 0, 0);
                acc[M][1] = __builtin_amdgcn_mfma_f32_16x16x32_bf16(af[mi], b[1][kk], acc[M][1], 0, 0, 0);
            }
        }
    }
}

// Layer 0: K=32 (kk=0 only; x lives at q==0 slots, W0 zero-padded beyond ch 2).
__device__ __forceinline__ void layer_K32(
    const unsigned short* __restrict__ wl, const float* __restrict__ bias,
    f32x4 (&acc)[16][2], bf16x8 (&b)[2][8], int q)
{
#pragma unroll
    for (int M = 0; M < 16; ++M) {
        float4 b4 = *(const float4*)(bias + M * 16 + q * 4);
        f32x4 bv = {b4.x, b4.y, b4.z, b4.w};
        acc[M][0] = bv;
        acc[M][1] = bv;
    }
#pragma unroll
    for (int Mh = 0; Mh < 2; ++Mh) {
        bf16x8 af[8];
#pragma unroll
        for (int mi = 0; mi < 8; ++mi)
            af[mi] = *(const bf16x8*)(wl + (Mh * 8 + mi) * 512);
#pragma unroll
        for (int mi = 0; mi < 8; ++mi) {
            const int M = Mh * 8 + mi;
            acc[M][0] = __builtin_amdgcn_mfma_f32_16x16x32_bf16(af[mi], b[0][0], acc[M][0], 0, 0, 0);
            acc[M][1] = __builtin_amdgcn_mfma_f32_16x16x32_bf16(af[mi], b[1][0], acc[M][1], 0, 0, 0);
        }
    }
}

__device__ __forceinline__ void epilogue(f32x4 (&acc)[16][2], bf16x8 (&b)[2][8]) {
#pragma unroll
    for (int nt = 0; nt < 2; ++nt)
#pragma unroll
        for (int kk = 0; kk < 8; ++kk)
            b[nt][kk] = sp_pack(acc[2 * kk][nt], acc[2 * kk + 1][nt]);
}

__global__ __launch_bounds__(256, 2)
void nhrep_main(const float* __restrict__ x, float* __restrict__ out,
                const unsigned short* __restrict__ wsW,
                const float* __restrict__ wsB, int npts)
{
    const int tid  = threadIdx.x;
    const int wave = tid >> 6, lane = tid & 63;
    const int q = lane >> 4, l15 = lane & 15;
    const int base = blockIdx.x * 128 + wave * 32;

    // my two points' x as bf16 (used for layer-0 entry and layer-3 splice)
    unsigned short xb[2][3];
#pragma unroll
    for (int nt = 0; nt < 2; ++nt) {
        const int pt = base + nt * 16 + l15;
        const bool ok = pt < npts;
#pragma unroll
        for (int c = 0; c < 3; ++c)
            xb[nt][c] = ok ? bf16_rne(x[pt * 3 + c]) : (unsigned short)0;
    }

    // activation frags (register-resident network state)
    bf16x8 b[2][8];
#pragma unroll
    for (int nt = 0; nt < 2; ++nt) {
        frag_u f;
        f.u4 = uint4{0u, 0u, 0u, 0u};
        if (q == 0) { f.s[0] = xb[nt][0]; f.s[1] = xb[nt][1]; f.s[2] = xb[nt][2]; }
        b[nt][0] = f.v;
#pragma unroll
        for (int kk = 1; kk < 8; ++kk) {
            frag_u z;
            z.u4 = uint4{0u, 0u, 0u, 0u};
            b[nt][kk] = z.v;
        }
    }

    f32x4 acc[16][2];

    // layer 0 (K=32)
    layer_K32(wsW + OFFW0 + lane * 8, wsB, acc, b, q);
    epilogue(acc, b);
    __syncthreads();   // convoy the block's waves for L1 reuse on W-streams

    // layers 1..6 (K=256), shared body (code size: keep I-cache happy)
#pragma unroll 1
    for (int l = 1; l <= 6; ++l) {
        layer_K256(wsW + OFFW1 + (l - 1) * 65536 + lane * 8, wsB + l * 256, acc, b, q);
        epilogue(acc, b);
        if (l == 3) {
            // splice raw x into logical channels 253..255 (M=15,q=3,r=1..3
            // -> b[nt][7] elems 5..7 at lanes q==3); W4 rows absorb scales
#pragma unroll
            for (int nt = 0; nt < 2; ++nt) {
                frag_u f;
                f.v = b[nt][7];
                if (q == 3) { f.s[5] = xb[nt][0]; f.s[6] = xb[nt][1]; f.s[7] = xb[nt][2]; }
                b[nt][7] = f.v;
            }
        }
        __syncthreads();
    }

    // layer 7: 256 -> 8 (W7 pre-scaled ln2/100, b7 raw, out rows 8..15 padded)
    f32x4 a7[2];
    {
        float4 b4 = *(const float4*)(wsB + OFFB7 + q * 4);   // quads 2,3: zeros
        f32x4 bv = {b4.x, b4.y, b4.z, b4.w};
        a7[0] = bv;
        a7[1] = bv;
        const unsigned short* wl = wsW + OFFW7 + lane * 8;
#pragma unroll
        for (int kk = 0; kk < 8; ++kk) {
            bf16x8 af = *(const bf16x8*)(wl + kk * 512);
            a7[0] = __builtin_amdgcn_mfma_f32_16x16x32_bf16(af, b[0][kk], a7[0], 0, 0, 0);
            a7[1] = __builtin_amdgcn_mfma_f32_16x16x32_bf16(af, b[1][kk], a7[1], 0, 0, 0);
        }
    }

    // CSG: lane (n,q0) holds ch0-3; fetch ch4-7 from lane n+16 (q1)
    float u[2][4];
#pragma unroll
    for (int nt = 0; nt < 2; ++nt)
#pragma unroll
        for (int r = 0; r < 4; ++r)
            u[nt][r] = __shfl(a7[nt][r], l15 + 16);

    if (q == 0) {
#pragma unroll
        for (int nt = 0; nt < 2; ++nt) {
            const int pt = base + nt * 16 + l15;
            if (pt < npts) {
                const float v0 = a7[nt][0], v1 = a7[nt][1], v2 = a7[nt][2], v3 = a7[nt][3];
                const float v4 = u[nt][0], v5 = u[nt][1], v6 = u[nt][2], v7 = u[nt][3];
                const float m23   = fminf(v2, v3);
                const float m67   = fmaxf(v6, v7);
                const float m4567 = fminf(fminf(v4, v5), m67);
                const float h     = fmaxf(fmaxf(v0, v1), fmaxf(m23, m4567));
                float* o = out + (long)pt * 9;
                o[0] = h;
                o[1] = v0; o[2] = v1; o[3] = v2; o[4] = v3;
                o[5] = v4; o[6] = v5; o[7] = v6; o[8] = v7;
            }
        }
    }
}

// ---------------------------------------------------------------------------
// Fused prepack with scale folding AND the sigma in-channel permutation:
// frag element (mt, kk, lane, j) = scale(l,k) * W_L[k][o], zero-padded, where
//   k = kk*32 + ((j>>2)<<4) + ((lane>>4)<<2) + (j&3)      <-- sigma
//   o = mt*16 + (lane&15)
// ---------------------------------------------------------------------------
struct PackArgs {
    const float* W[8];
    const float* b[8];
};

#define TOTAL_FRAGS 50688
#define TOTAL_BIAS  1808

__global__ void prepack_all(PackArgs args, unsigned short* __restrict__ dstW,
                            float* __restrict__ dstB)
{
    const int t = blockIdx.x * blockDim.x + threadIdx.x;
    const int FB[9]  = {0, 1024, 9216, 17408, 25600, 33792, 41984, 50176, 50688};
    const int KKs[8] = {1, 8, 8, 8, 8, 8, 8, 8};
    const int ind[8] = {3, 256, 256, 256, 256, 256, 256, 256};
    const int outd[8]= {256, 256, 256, 253, 256, 256, 256, 8};

    if (t < TOTAL_FRAGS) {
        int l = 0;
        while (t >= FB[l + 1]) ++l;
        const int f    = t - FB[l];
        const int lane = f & 63;
        const int kk   = (f >> 6) % KKs[l];
        const int mt   = f / (64 * KKs[l]);
        const int o    = mt * 16 + (lane & 15);
        const int q    = lane >> 4;
        const float* W = args.W[l];
        const int in_d = ind[l], out_d = outd[l];

        unsigned short v[8];
#pragma unroll
        for (int j = 0; j < 8; ++j) {
            const int k = kk * 32 + ((j >> 2) << 4) + (q << 2) + (j & 3);
            float w = 0.0f;
            if (k < in_d && o < out_d) {
                float sc = 1.0f;
                if (l == 0) sc = SCALE_T2;
                else if (l == 4) sc = (k < 253) ? INV_SQRT2 : (SCALE_T2 * INV_SQRT2);
                else if (l == 7) sc = LN2_100;
                w = W[k * out_d + o] * sc;
            }
            unsigned int u = __float_as_uint(w);
            v[j] = (unsigned short)((u + 0x7FFFu + ((u >> 16) & 1u)) >> 16);
        }
        uint4 p;
        p.x = (unsigned int)v[0] | ((unsigned int)v[1] << 16);
        p.y = (unsigned int)v[2] | ((unsigned int)v[3] << 16);
        p.z = (unsigned int)v[4] | ((unsigned int)v[5] << 16);
        p.w = (unsigned int)v[6] | ((unsigned int)v[7] << 16);
        *(uint4*)(dstW + (long)t * 8) = p;
    } else if (t < TOTAL_FRAGS + TOTAL_BIAS) {
        const int u = t - TOTAL_FRAGS;
        const int l = (u < 1792) ? (u >> 8) : 7;
        const int idx = (l < 7) ? (u & 255) : (u - 1792);
        const float sc = (l < 7) ? SCALE_T2 : 1.0f;   // b7 stays in output units
        dstB[u] = (idx < outd[l]) ? args.b[l][idx] * sc : 0.0f;
    }
}

extern "C" void kernel_launch(void* const* d_in, const int* in_sizes, int n_in,
                              void* d_out, int out_size, void* d_ws, size_t ws_size,
                              hipStream_t stream)
{
    const float* x = (const float*)d_in[0];
    unsigned short* wsW = (unsigned short*)d_ws;
    float* wsB = (float*)((char*)d_ws + WSB_BYTE_OFF);

    PackArgs pa;
    for (int l = 0; l < 8; ++l) {
        pa.W[l] = (const float*)d_in[1 + 2 * l];
        pa.b[l] = (const float*)d_in[2 + 2 * l];
    }
    const int ptot = TOTAL_FRAGS + TOTAL_BIAS;
    prepack_all<<<(ptot + 255) / 256, 256, 0, stream>>>(pa, wsW, wsB);

    const int npts = in_sizes[0] / 3;                 // 100000
    const int nblk = (npts + 127) / 128;              // 782 blocks x 4 waves x 32 pts
    nhrep_main<<<nblk, 256, 0, stream>>>(x, (float*)d_out, wsW, wsB, npts);
}

// Round 8
// 256.952 us; speedup vs baseline: 1.3091x; 1.3091x over previous
//
#include <hip/hip_runtime.h>
#include <hip/hip_bf16.h>

// ---------------------------------------------------------------------------
// NHRepNet fused forward, Round 8: wide channel strips at the 128-reg tier.
//
// Lessons baked in:
//  R4 (best, 138us): 32-ch waves -> 8x LDS act-read redundancy; pipes additive.
//  R5: XOR swizzle useless (b128 "conflicts" are structural); ping-pong spilled.
//  R6: MT=4 at the 64-reg tier -> spill (145MB scratch). NEVER exceed the tier.
//  R7: private weight streams @ 2 waves/SIMD -> L1/L2 BW starvation.
//
// R8: 512-thr blocks, 8 waves; wave owns 128 ch (MT=8, acc[8][2]=64 AGPR) for
// 32 pts; 4 point-groups -> 128-pt blocks. __launch_bounds__(512,4) -> 128-reg
// cap, ~120 needed. LDS act in-place (69.6KB, 2 blk/CU, 16 waves/CU). B-read
// redundancy 2x (was 8x). Mixed grid: 512x128-pt + 539x64-pt (MT=4) tail.
// Weights via per-wave global loads of prepacked frags (L1-shared across
// point-groups, convoyed by the per-layer barriers).
// ---------------------------------------------------------------------------

using bf16x8 = __attribute__((ext_vector_type(8))) __bf16;
using f32x4  = __attribute__((ext_vector_type(4))) float;

#define LDA 264   // padded activation row stride (bf16)

#define OFFW0 0
#define OFFW1 8192
#define OFFW2 73728
#define OFFW3 139264
#define OFFW4 204800
#define OFFW5 270336
#define OFFW6 335872
#define OFFW7 401408
#define WSB_BYTE_OFF 811008   // fp32 bias region
#define OFFB7 1792            // L0..L6 at l*256; L7 at 1792 (16 floats, padded)

#define SCALE_T2 144.26950408889634f      // 100*log2(e)
#define INV_SQRT2 0.70710678118654752f
#define LN2_100 0.0069314718055994531f    // ln2/100

__device__ __forceinline__ float fast_exp2(float x) {
#if __has_builtin(__builtin_amdgcn_exp2f)
    return __builtin_amdgcn_exp2f(x);
#else
    return exp2f(x);
#endif
}
__device__ __forceinline__ float fast_log2(float x) {
#if __has_builtin(__builtin_amdgcn_logf)
    return __builtin_amdgcn_logf(x);
#else
    return log2f(x);
#endif
}

// a2 = max(t2,0) + log2(1 + 2^-|t2|)   (t2-domain; scales folded into weights)
__device__ __forceinline__ float softplus_t2(float t2) {
    float e = fast_exp2(-fabsf(t2));
    float l = fast_log2(1.0f + e);
    return fmaxf(t2, 0.0f) + l;
}

__device__ __forceinline__ unsigned short bf16_rne(float f) {
    unsigned int u = __float_as_uint(f);
    unsigned int r = u + 0x7FFFu + ((u >> 16) & 1u);
    return (unsigned short)(r >> 16);
}

// One 256-out layer, in-place on act[MT*16][LDA]. 8 waves: NSTRIP=16/MT
// channel strips x (8/NSTRIP) point-groups of 32 pts. Wave -> strip =
// wave & (NSTRIP-1), pg = wave / NSTRIP. MODE 1 = layer-3 splice (raw x into
// ch 253..255; W4 rows absorb all scales).
template <int KK, int MODE, int MT>
__device__ __forceinline__ void layer_mm(
    const unsigned short* __restrict__ wfrag,
    const float* __restrict__ bias,
    unsigned short* act, const float* xst,
    int wave, int lane)
{
    constexpr int NSTRIP = 16 / MT;            // 2 (MT=8) or 4 (MT=4)
    const int strip = wave & (NSTRIP - 1);
    const int pg    = wave / NSTRIP;
    const int quad  = lane >> 4;
    const int l15   = lane & 15;
    const int row0  = pg * 32 + l15;           // nt adds 16

    f32x4 acc[MT][2];
#pragma unroll
    for (int i = 0; i < MT; ++i) {
        const int chb = (strip * MT + i) * 16 + quad * 4;
        const float4 b4 = *(const float4*)(bias + chb);
#pragma unroll
        for (int nt = 0; nt < 2; ++nt)
            acc[i][nt] = f32x4{b4.x, b4.y, b4.z, b4.w};
    }

    // per-wave A base; offsets (i*KK+kk)*512 elems are compile-time constants
    const unsigned short* wbase = wfrag + (strip * MT * KK * 64 + lane) * 8;

#pragma unroll
    for (int kk = 0; kk < KK; ++kk) {
        bf16x8 bfr[2];
#pragma unroll
        for (int nt = 0; nt < 2; ++nt)
            bfr[nt] = *(const bf16x8*)(act + (row0 + nt * 16) * LDA + kk * 32 + quad * 8);
#pragma unroll
        for (int i = 0; i < MT; ++i) {
            bf16x8 afr = *(const bf16x8*)(wbase + (i * KK + kk) * 512);
            acc[i][0] = __builtin_amdgcn_mfma_f32_16x16x32_bf16(afr, bfr[0], acc[i][0], 0, 0, 0);
            acc[i][1] = __builtin_amdgcn_mfma_f32_16x16x32_bf16(afr, bfr[1], acc[i][1], 0, 0, 0);
        }
    }

    __syncthreads();   // all waves done READING act

#pragma unroll
    for (int i = 0; i < MT; ++i) {
        const int chb = (strip * MT + i) * 16 + quad * 4;
#pragma unroll
        for (int nt = 0; nt < 2; ++nt) {
            const int pt = row0 + nt * 16;
            float vv[4];
#pragma unroll
            for (int r = 0; r < 4; ++r) {
                float s = softplus_t2(acc[i][nt][r]);
                if (MODE == 1) {
                    const int ch = chb + r;
                    if (ch >= 253)  // splice raw x (W4 rows absorb scales)
                        s = xst[pt * 4 + (ch - 253)];
                }
                vv[r] = s;
            }
            __hip_bfloat162 p01 = __float22bfloat162_rn(float2{vv[0], vv[1]});
            __hip_bfloat162 p23 = __float22bfloat162_rn(float2{vv[2], vv[3]});
            uint2 pk;
            pk.x = *(unsigned int*)&p01;
            pk.y = *(unsigned int*)&p23;
            *(uint2*)(act + pt * LDA + chb) = pk;
        }
    }

    __syncthreads();   // writes visible before next layer reads
}

// Full network for one tile of NPT = MT*16 points (MT=8 -> 128, MT=4 -> 64).
template <int MT>
__device__ __forceinline__ void run_net(
    const float* __restrict__ x, float* __restrict__ out,
    const unsigned short* __restrict__ wsW, const float* __restrict__ wsB,
    unsigned short* act, float* xst,
    int base_pt, int npts, int tid)
{
    constexpr int NPT = MT * 16;
    const int wave = tid >> 6, lane = tid & 63;
    const int quad = lane >> 4, l15 = lane & 15;

    // stage x into act channels 0..2, zero-pad to 32 (K-pad for layer 0)
    for (int i = tid; i < NPT * 32; i += 512) {
        const int pt = i >> 5, ch = i & 31;
        const int ptg = base_pt + pt;
        float v = 0.0f;
        if (ch < 3 && ptg < npts) v = x[ptg * 3 + ch];
        act[pt * LDA + ch] = bf16_rne(v);
        if (ch < 4) xst[pt * 4 + ch] = (ch < 3) ? v : 0.0f;
    }
    __syncthreads();

    layer_mm<1, 0, MT>(wsW + OFFW0, wsB + 0 * 256, act, xst, wave, lane);
    layer_mm<8, 0, MT>(wsW + OFFW1, wsB + 1 * 256, act, xst, wave, lane);
    layer_mm<8, 0, MT>(wsW + OFFW2, wsB + 2 * 256, act, xst, wave, lane);
    layer_mm<8, 1, MT>(wsW + OFFW3, wsB + 3 * 256, act, xst, wave, lane);
    layer_mm<8, 0, MT>(wsW + OFFW4, wsB + 4 * 256, act, xst, wave, lane);
    layer_mm<8, 0, MT>(wsW + OFFW5, wsB + 5 * 256, act, xst, wave, lane);
    layer_mm<8, 0, MT>(wsW + OFFW6, wsB + 6 * 256, act, xst, wave, lane);

    // layer 7: 256 -> 8 (W7 pre-scaled ln2/100, b7 raw). Wave w handles pts
    // [w*16, w*16+16) while w*16 < NPT. act not written again -> no barrier.
    if (wave < NPT / 16) {
        const float4 b4 = *(const float4*)(wsB + OFFB7 + quad * 4);  // quads>=2: zeros
        f32x4 acc = f32x4{b4.x, b4.y, b4.z, b4.w};
        const unsigned short* w7 = wsW + OFFW7;
#pragma unroll
        for (int kk = 0; kk < 8; ++kk) {
            bf16x8 bfr = *(const bf16x8*)(act + (wave * 16 + l15) * LDA + kk * 32 + quad * 8);
            bf16x8 afr = *(const bf16x8*)(w7 + (kk * 64 + lane) * 8);
            acc = __builtin_amdgcn_mfma_f32_16x16x32_bf16(afr, bfr, acc, 0, 0, 0);
        }
        // quad0 lanes hold ch0-3, quad1 ch4-7 for pt = wave*16+l15
        float u0 = __shfl(acc[0], l15 + 16);
        float u1 = __shfl(acc[1], l15 + 16);
        float u2 = __shfl(acc[2], l15 + 16);
        float u3 = __shfl(acc[3], l15 + 16);
        if (quad == 0) {
            const int ptg = base_pt + wave * 16 + l15;
            if (ptg < npts) {
                const float v0 = acc[0], v1 = acc[1], v2 = acc[2], v3 = acc[3];
                const float v4 = u0, v5 = u1, v6 = u2, v7 = u3;
                const float m23   = fminf(v2, v3);
                const float m67   = fmaxf(v6, v7);
                const float m4567 = fminf(fminf(v4, v5), m67);
                const float h     = fmaxf(fmaxf(v0, v1), fmaxf(m23, m4567));
                float* o = out + (long)ptg * 9;
                o[0] = h;
                o[1] = v0; o[2] = v1; o[3] = v2; o[4] = v3;
                o[5] = v4; o[6] = v5; o[7] = v6; o[8] = v7;
            }
        }
    }
}

__global__ __launch_bounds__(512, 4)
void nhrep_main(const float* __restrict__ x, float* __restrict__ out,
                const unsigned short* __restrict__ wsW,
                const float* __restrict__ wsB, int npts, int nbig)
{
    __shared__ unsigned short act[128 * LDA];  // 67584 B
    __shared__ float xst[128 * 4];             // 2048 B -> 69632 B (2 blk/CU)
    const int b = blockIdx.x;
    if (b < nbig) {
        run_net<8>(x, out, wsW, wsB, act, xst, b * 128, npts, threadIdx.x);
    } else {
        run_net<4>(x, out, wsW, wsB, act, xst, nbig * 128 + (b - nbig) * 64,
                   npts, threadIdx.x);
    }
}

// ---------------------------------------------------------------------------
// Fused prepack with scale folding (R4-proven, identity k-mapping).
// Frag (mt,kk,lane,j) = scale(l,k) * W^T[mt*16+(lane&15)][kk*32+(lane>>4)*8+j]
// ---------------------------------------------------------------------------
struct PackArgs {
    const float* W[8];
    const float* b[8];
};

#define TOTAL_FRAGS 50688
#define TOTAL_BIAS  1808

__global__ void prepack_all(PackArgs args, unsigned short* __restrict__ dstW,
                            float* __restrict__ dstB)
{
    const int t = blockIdx.x * blockDim.x + threadIdx.x;
    const int FB[9]  = {0, 1024, 9216, 17408, 25600, 33792, 41984, 50176, 50688};
    const int KKs[8] = {1, 8, 8, 8, 8, 8, 8, 8};
    const int ind[8] = {3, 256, 256, 256, 256, 256, 256, 256};
    const int outd[8]= {256, 256, 256, 253, 256, 256, 256, 8};

    if (t < TOTAL_FRAGS) {
        int l = 0;
        while (t >= FB[l + 1]) ++l;
        const int f    = t - FB[l];
        const int lane = f & 63;
        const int kk   = (f >> 6) % KKs[l];
        const int mt   = f / (64 * KKs[l]);
        const int o    = mt * 16 + (lane & 15);
        const int kb   = kk * 32 + (lane >> 4) * 8;
        const float* W = args.W[l];
        const int in_d = ind[l], out_d = outd[l];

        unsigned short v[8];
#pragma unroll
        for (int j = 0; j < 8; ++j) {
            const int k = kb + j;
            float w = 0.0f;
            if (k < in_d && o < out_d) {
                float sc = 1.0f;
                if (l == 0) sc = SCALE_T2;
                else if (l == 4) sc = (k < 253) ? INV_SQRT2 : (SCALE_T2 * INV_SQRT2);
                else if (l == 7) sc = LN2_100;
                w = W[k * out_d + o] * sc;
            }
            unsigned int u = __float_as_uint(w);
            v[j] = (unsigned short)((u + 0x7FFFu + ((u >> 16) & 1u)) >> 16);
        }
        uint4 p;
        p.x = (unsigned int)v[0] | ((unsigned int)v[1] << 16);
        p.y = (unsigned int)v[2] | ((unsigned int)v[3] << 16);
        p.z = (unsigned int)v[4] | ((unsigned int)v[5] << 16);
        p.w = (unsigned int)v[6] | ((unsigned int)v[7] << 16);
        *(uint4*)(dstW + (long)t * 8) = p;
    } else if (t < TOTAL_FRAGS + TOTAL_BIAS) {
        const int u = t - TOTAL_FRAGS;
        const int l = (u < 1792) ? (u >> 8) : 7;
        const int idx = (l < 7) ? (u & 255) : (u - 1792);
        const float sc = (l < 7) ? SCALE_T2 : 1.0f;   // b7 stays in output units
        dstB[u] = (idx < outd[l]) ? args.b[l][idx] * sc : 0.0f;
    }
}

extern "C" void kernel_launch(void* const* d_in, const int* in_sizes, int n_in,
                              void* d_out, int out_size, void* d_ws, size_t ws_size,
                              hipStream_t stream)
{
    const float* x = (const float*)d_in[0];
    unsigned short* wsW = (unsigned short*)d_ws;
    float* wsB = (float*)((char*)d_ws + WSB_BYTE_OFF);

    PackArgs pa;
    for (int l = 0; l < 8; ++l) {
        pa.W[l] = (const float*)d_in[1 + 2 * l];
        pa.b[l] = (const float*)d_in[2 + 2 * l];
    }
    const int ptot = TOTAL_FRAGS + TOTAL_BIAS;
    prepack_all<<<(ptot + 255) / 256, 256, 0, stream>>>(pa, wsW, wsB);

    const int npts = in_sizes[0] / 3;            // 100000
    // Mixed grid: one full resident round of 128-pt blocks (2 blk/CU * 256 CU
    // = 512), remainder as 64-pt blocks.
    int nbig = npts / 128;
    if (nbig > 512) nbig = 512;
    const int rem = npts - nbig * 128;
    const int nsmall = (rem + 63) / 64;
    nhrep_main<<<nbig + nsmall, 512, 0, stream>>>(x, (float*)d_out, wsW, wsB,
                                                  npts, nbig);
}

// Round 9
// 203.598 us; speedup vs baseline: 1.6522x; 1.2621x over previous
//
#include <hip/hip_runtime.h>
#include <hip/hip_bf16.h>

// ---------------------------------------------------------------------------
// NHRepNet fused forward, Round 9: R4 structure with nt=4 (A-traffic halved).
//
// Model (from R1-R8 counters): per-point A-frag bytes depend ONLY on
// points-per-wave: per 32 pts the full 128KB layer W is read by someone.
//   R4 (nt=2): A = 4KB/pt/layer -> 2.8GB through L1 port (64B/cyc/CU) = 73us
//   <- the binding pipe. LDS-B 36us, VALU ~55us, MFMA 10us. Wall 138us.
// R8 failed because MT widening leaves A-traffic unchanged; only nt cuts it.
// R9: C=32 (MT=2), nt=4 -> A = 2KB/pt = 1.4GB = ~36us L1. acc[2][4]=32 AGPR
// + ~45 VGPR = ~80 unified -> 128-reg tier with HEADROOM (R6 lesson: never
// sit at the cap), 4 waves/SIMD, 2 blocks/CU. Tile 64 pts x 8 strip-waves,
// 1563 blocks = 3.05 resident rounds (fill ok, no mixed grid).
// Keep from R4: in-place act (LDA=264), 2 barriers/layer, t2-domain scale
// folding, proven prepack.
// ---------------------------------------------------------------------------

using bf16x8 = __attribute__((ext_vector_type(8))) __bf16;
using f32x4  = __attribute__((ext_vector_type(4))) float;

#define LDA 264   // padded activation row stride (bf16)

#define OFFW0 0
#define OFFW1 8192
#define OFFW2 73728
#define OFFW3 139264
#define OFFW4 204800
#define OFFW5 270336
#define OFFW6 335872
#define OFFW7 401408
#define WSB_BYTE_OFF 811008   // fp32 bias region
#define OFFB7 1792            // L0..L6 at l*256; L7 at 1792 (16 floats, padded)

#define SCALE_T2 144.26950408889634f      // 100*log2(e)
#define INV_SQRT2 0.70710678118654752f
#define LN2_100 0.0069314718055994531f    // ln2/100

__device__ __forceinline__ float fast_exp2(float x) {
#if __has_builtin(__builtin_amdgcn_exp2f)
    return __builtin_amdgcn_exp2f(x);
#else
    return exp2f(x);
#endif
}
__device__ __forceinline__ float fast_log2(float x) {
#if __has_builtin(__builtin_amdgcn_logf)
    return __builtin_amdgcn_logf(x);
#else
    return log2f(x);
#endif
}

// a2 = max(t2,0) + log2(1 + 2^-|t2|)   (t2-domain; scales folded into weights)
__device__ __forceinline__ float softplus_t2(float t2) {
    float e = fast_exp2(-fabsf(t2));
    float l = fast_log2(1.0f + e);
    return fmaxf(t2, 0.0f) + l;
}

__device__ __forceinline__ unsigned short bf16_rne(float f) {
    unsigned int u = __float_as_uint(f);
    unsigned int r = u + 0x7FFFu + ((u >> 16) & 1u);
    return (unsigned short)(r >> 16);
}

// One 256-out layer, in-place on act[64][LDA]. 8 waves = 8 channel strips
// (wave owns ch [wave*32, wave*32+32)) covering all 64 points (nt=0..3).
// MODE 1 = layer-3 splice (raw x into ch 253..255; W4 rows absorb scales).
template <int KK, int MODE>
__device__ __forceinline__ void layer_mm(
    const unsigned short* __restrict__ wfrag,
    const float* __restrict__ bias,
    unsigned short* act, const float* xst,
    int wave, int lane)
{
    const int quad = lane >> 4;
    const int l15  = lane & 15;

    f32x4 acc[2][4];
#pragma unroll
    for (int i = 0; i < 2; ++i) {
        const int chb = (wave * 2 + i) * 16 + quad * 4;
        const float4 b4 = *(const float4*)(bias + chb);
#pragma unroll
        for (int nt = 0; nt < 4; ++nt)
            acc[i][nt] = f32x4{b4.x, b4.y, b4.z, b4.w};
    }

    const unsigned short* wbase = wfrag + (wave * 2 * KK * 64 + lane) * 8;

#pragma unroll
    for (int kk = 0; kk < KK; ++kk) {
        bf16x8 bfr[4];
#pragma unroll
        for (int nt = 0; nt < 4; ++nt)
            bfr[nt] = *(const bf16x8*)(act + (nt * 16 + l15) * LDA + kk * 32 + quad * 8);
#pragma unroll
        for (int i = 0; i < 2; ++i) {
            bf16x8 afr = *(const bf16x8*)(wbase + (i * KK + kk) * 512);
#pragma unroll
            for (int nt = 0; nt < 4; ++nt)
                acc[i][nt] = __builtin_amdgcn_mfma_f32_16x16x32_bf16(afr, bfr[nt], acc[i][nt], 0, 0, 0);
        }
    }

    __syncthreads();   // all waves done READING act

#pragma unroll
    for (int i = 0; i < 2; ++i) {
        const int chb = (wave * 2 + i) * 16 + quad * 4;
#pragma unroll
        for (int nt = 0; nt < 4; ++nt) {
            const int pt = nt * 16 + l15;
            float vv[4];
#pragma unroll
            for (int r = 0; r < 4; ++r) {
                float s = softplus_t2(acc[i][nt][r]);
                if (MODE == 1) {
                    const int ch = chb + r;
                    if (ch >= 253)  // splice raw x (W4 rows absorb scales)
                        s = xst[pt * 4 + (ch - 253)];
                }
                vv[r] = s;
            }
            __hip_bfloat162 p01 = __float22bfloat162_rn(float2{vv[0], vv[1]});
            __hip_bfloat162 p23 = __float22bfloat162_rn(float2{vv[2], vv[3]});
            uint2 pk;
            pk.x = *(unsigned int*)&p01;
            pk.y = *(unsigned int*)&p23;
            *(uint2*)(act + pt * LDA + chb) = pk;
        }
    }

    __syncthreads();   // writes visible before next layer reads
}

__global__ __launch_bounds__(512, 4)
void nhrep_main(const float* __restrict__ x, float* __restrict__ out,
                const unsigned short* __restrict__ wsW,
                const float* __restrict__ wsB, int npts)
{
    __shared__ unsigned short act[64 * LDA];   // 33792 B
    __shared__ float xst[64 * 4];              // 1024 B -> 34816 B total
    const int tid  = threadIdx.x;
    const int wave = tid >> 6, lane = tid & 63;
    const int quad = lane >> 4, l15 = lane & 15;
    const int base_pt = blockIdx.x * 64;

    // stage x into act channels 0..2, zero-pad to 32 (K-pad for layer 0)
    for (int i = tid; i < 64 * 32; i += 512) {
        const int pt = i >> 5, ch = i & 31;
        const int ptg = base_pt + pt;
        float v = 0.0f;
        if (ch < 3 && ptg < npts) v = x[ptg * 3 + ch];
        act[pt * LDA + ch] = bf16_rne(v);
        if (ch < 4) xst[pt * 4 + ch] = (ch < 3) ? v : 0.0f;
    }
    __syncthreads();

    layer_mm<1, 0>(wsW + OFFW0, wsB + 0 * 256, act, xst, wave, lane);
    layer_mm<8, 0>(wsW + OFFW1, wsB + 1 * 256, act, xst, wave, lane);
    layer_mm<8, 0>(wsW + OFFW2, wsB + 2 * 256, act, xst, wave, lane);
    layer_mm<8, 1>(wsW + OFFW3, wsB + 3 * 256, act, xst, wave, lane);
    layer_mm<8, 0>(wsW + OFFW4, wsB + 4 * 256, act, xst, wave, lane);
    layer_mm<8, 0>(wsW + OFFW5, wsB + 5 * 256, act, xst, wave, lane);
    layer_mm<8, 0>(wsW + OFFW6, wsB + 6 * 256, act, xst, wave, lane);

    // layer 7: 256 -> 8 (W7 pre-scaled ln2/100, b7 raw). Waves 0..3 handle
    // 16 pts each; act not written again -> no barrier.
    if (wave < 4) {
        const float4 b4 = *(const float4*)(wsB + OFFB7 + quad * 4);  // quads>=2: zeros
        f32x4 acc = f32x4{b4.x, b4.y, b4.z, b4.w};
        const unsigned short* w7 = wsW + OFFW7;
#pragma unroll
        for (int kk = 0; kk < 8; ++kk) {
            bf16x8 bfr = *(const bf16x8*)(act + (wave * 16 + l15) * LDA + kk * 32 + quad * 8);
            bf16x8 afr = *(const bf16x8*)(w7 + (kk * 64 + lane) * 8);
            acc = __builtin_amdgcn_mfma_f32_16x16x32_bf16(afr, bfr, acc, 0, 0, 0);
        }
        // quad0 lanes hold ch0-3, quad1 ch4-7 for pt = wave*16+l15
        float u0 = __shfl(acc[0], l15 + 16);
        float u1 = __shfl(acc[1], l15 + 16);
        float u2 = __shfl(acc[2], l15 + 16);
        float u3 = __shfl(acc[3], l15 + 16);
        if (quad == 0) {
            const int ptg = base_pt + wave * 16 + l15;
            if (ptg < npts) {
                const float v0 = acc[0], v1 = acc[1], v2 = acc[2], v3 = acc[3];
                const float v4 = u0, v5 = u1, v6 = u2, v7 = u3;
                const float m23   = fminf(v2, v3);
                const float m67   = fmaxf(v6, v7);
                const float m4567 = fminf(fminf(v4, v5), m67);
                const float h     = fmaxf(fmaxf(v0, v1), fmaxf(m23, m4567));
                float* o = out + (long)ptg * 9;
                o[0] = h;
                o[1] = v0; o[2] = v1; o[3] = v2; o[4] = v3;
                o[5] = v4; o[6] = v5; o[7] = v6; o[8] = v7;
            }
        }
    }
}

// ---------------------------------------------------------------------------
// Fused prepack with scale folding (R4-proven, identity k-mapping).
// Frag (mt,kk,lane,j) = scale(l,k) * W^T[mt*16+(lane&15)][kk*32+(lane>>4)*8+j]
// ---------------------------------------------------------------------------
struct PackArgs {
    const float* W[8];
    const float* b[8];
};

#define TOTAL_FRAGS 50688
#define TOTAL_BIAS  1808

__global__ void prepack_all(PackArgs args, unsigned short* __restrict__ dstW,
                            float* __restrict__ dstB)
{
    const int t = blockIdx.x * blockDim.x + threadIdx.x;
    const int FB[9]  = {0, 1024, 9216, 17408, 25600, 33792, 41984, 50176, 50688};
    const int KKs[8] = {1, 8, 8, 8, 8, 8, 8, 8};
    const int ind[8] = {3, 256, 256, 256, 256, 256, 256, 256};
    const int outd[8]= {256, 256, 256, 253, 256, 256, 256, 8};

    if (t < TOTAL_FRAGS) {
        int l = 0;
        while (t >= FB[l + 1]) ++l;
        const int f    = t - FB[l];
        const int lane = f & 63;
        const int kk   = (f >> 6) % KKs[l];
        const int mt   = f / (64 * KKs[l]);
        const int o    = mt * 16 + (lane & 15);
        const int kb   = kk * 32 + (lane >> 4) * 8;
        const float* W = args.W[l];
        const int in_d = ind[l], out_d = outd[l];

        unsigned short v[8];
#pragma unroll
        for (int j = 0; j < 8; ++j) {
            const int k = kb + j;
            float w = 0.0f;
            if (k < in_d && o < out_d) {
                float sc = 1.0f;
                if (l == 0) sc = SCALE_T2;
                else if (l == 4) sc = (k < 253) ? INV_SQRT2 : (SCALE_T2 * INV_SQRT2);
                else if (l == 7) sc = LN2_100;
                w = W[k * out_d + o] * sc;
            }
            unsigned int u = __float_as_uint(w);
            v[j] = (unsigned short)((u + 0x7FFFu + ((u >> 16) & 1u)) >> 16);
        }
        uint4 p;
        p.x = (unsigned int)v[0] | ((unsigned int)v[1] << 16);
        p.y = (unsigned int)v[2] | ((unsigned int)v[3] << 16);
        p.z = (unsigned int)v[4] | ((unsigned int)v[5] << 16);
        p.w = (unsigned int)v[6] | ((unsigned int)v[7] << 16);
        *(uint4*)(dstW + (long)t * 8) = p;
    } else if (t < TOTAL_FRAGS + TOTAL_BIAS) {
        const int u = t - TOTAL_FRAGS;
        const int l = (u < 1792) ? (u >> 8) : 7;
        const int idx = (l < 7) ? (u & 255) : (u - 1792);
        const float sc = (l < 7) ? SCALE_T2 : 1.0f;   // b7 stays in output units
        dstB[u] = (idx < outd[l]) ? args.b[l][idx] * sc : 0.0f;
    }
}

extern "C" void kernel_launch(void* const* d_in, const int* in_sizes, int n_in,
                              void* d_out, int out_size, void* d_ws, size_t ws_size,
                              hipStream_t stream)
{
    const float* x = (const float*)d_in[0];
    unsigned short* wsW = (unsigned short*)d_ws;
    float* wsB = (float*)((char*)d_ws + WSB_BYTE_OFF);

    PackArgs pa;
    for (int l = 0; l < 8; ++l) {
        pa.W[l] = (const float*)d_in[1 + 2 * l];
        pa.b[l] = (const float*)d_in[2 + 2 * l];
    }
    const int ptot = TOTAL_FRAGS + TOTAL_BIAS;
    prepack_all<<<(ptot + 255) / 256, 256, 0, stream>>>(pa, wsW, wsB);

    const int npts = in_sizes[0] / 3;            // 100000
    const int nblk = (npts + 63) / 64;           // 1563
    nhrep_main<<<nblk, 512, 0, stream>>>(x, (float*)d_out, wsW, wsB, npts);
}